// Round 1
// baseline (174.612 us; speedup 1.0000x reference)
//
#include <hip/hip_runtime.h>
#include <stdint.h>

#define NH 16
#define HD 64
#define SEQ 2048
#define SCALE 0.125f

typedef __attribute__((ext_vector_type(8))) short bf16x8;
typedef __attribute__((ext_vector_type(4))) short bf16x4;
typedef __attribute__((ext_vector_type(4))) float f32x4;
typedef unsigned short u16;

__device__ __forceinline__ u16 f2bf(float f) {
  union { float f; uint32_t u; } v; v.f = f;
  uint32_t u = v.u;
  u += 0x7fffu + ((u >> 16) & 1u);   // RNE
  return (u16)(u >> 16);
}

__device__ __forceinline__ void gload_lds16(const u16* g, u16* l) {
  __builtin_amdgcn_global_load_lds((__attribute__((address_space(1))) void*)g,
                                   (__attribute__((address_space(3))) void*)l,
                                   16, 0, 0);
}

// ---------------- fp32 -> bf16 convert ----------------
__global__ void cvt_kernel(const float* __restrict__ in, u16* __restrict__ out, int n4) {
  int i = blockIdx.x * blockDim.x + threadIdx.x;
  int stride = gridDim.x * blockDim.x;
  for (; i < n4; i += stride) {
    float4 v = ((const float4*)in)[i];
    bf16x4 o;
    o[0] = (short)f2bf(v.x); o[1] = (short)f2bf(v.y);
    o[2] = (short)f2bf(v.z); o[3] = (short)f2bf(v.w);
    ((bf16x4*)out)[i] = o;
  }
}

// ---------------- C = A(MxK) @ B(NxK)^T, bf16 in, CT out ----------------
// 128x128 tile, 4 waves (2x2), BK=32, global_load_lds staging with XOR chunk
// swizzle (slot = chunk ^ ((row>>1)&3)) applied on the pre-swizzled global
// source (LDS stays linear) and on the ds_read side.
template <typename CT>
__global__ __launch_bounds__(256) void gemm_bt(const u16* __restrict__ A,
                                               const u16* __restrict__ B,
                                               CT* __restrict__ C,
                                               int N, int K) {
  __shared__ u16 As[128 * 32];
  __shared__ u16 Bs[128 * 32];
  const int tid = threadIdx.x;
  const int wid = tid >> 6;
  const int lane = tid & 63;
  const int lg = lane >> 4, lq = lane & 15;
  const int wr = wid >> 1, wc = wid & 1;
  const int tm = blockIdx.y, tn = blockIdx.x;

  f32x4 acc[4][4];
#pragma unroll
  for (int m = 0; m < 4; m++)
#pragma unroll
    for (int n = 0; n < 4; n++)
#pragma unroll
      for (int e = 0; e < 4; e++) acc[m][n][e] = 0.f;

  const int r0 = tid >> 2;                    // 0..63
  const int s0 = tid & 3;                     // chunk slot within row
  const int sc = (s0 ^ ((r0 >> 1) & 3)) * 8;  // pre-swizzled source column
  const u16* gA0 = A + (size_t)(tm * 128 + r0) * K + sc;
  const u16* gA1 = A + (size_t)(tm * 128 + r0 + 64) * K + sc;  // (r0+64)>>1 same &3
  const u16* gB0 = B + (size_t)(tn * 128 + r0) * K + sc;
  const u16* gB1 = B + (size_t)(tn * 128 + r0 + 64) * K + sc;
  u16* lA = As + wid * 512;   // wave-uniform 1KB chunk base
  u16* lB = Bs + wid * 512;

  const int rslot = (lg ^ ((lq >> 1) & 3)) * 8;  // read slot (row-dep part = lq only)

  for (int k0 = 0; k0 < K; k0 += 32) {
    __syncthreads();
    gload_lds16(gA0 + k0, lA);
    gload_lds16(gA1 + k0, lA + 2048);
    gload_lds16(gB0 + k0, lB);
    gload_lds16(gB1 + k0, lB + 2048);
    __syncthreads();

    bf16x8 af[4], bfr[4];
#pragma unroll
    for (int m = 0; m < 4; m++)
      af[m] = *(const bf16x8*)(As + (wr * 64 + m * 16 + lq) * 32 + rslot);
#pragma unroll
    for (int n = 0; n < 4; n++)
      bfr[n] = *(const bf16x8*)(Bs + (wc * 64 + n * 16 + lq) * 32 + rslot);
#pragma unroll
    for (int m = 0; m < 4; m++)
#pragma unroll
      for (int n = 0; n < 4; n++)
        acc[m][n] = __builtin_amdgcn_mfma_f32_16x16x32_bf16(af[m], bfr[n], acc[m][n], 0, 0, 0);
  }

#pragma unroll
  for (int m = 0; m < 4; m++) {
    const int row = tm * 128 + wr * 64 + m * 16 + lg * 4;
#pragma unroll
    for (int i = 0; i < 4; i++) {
      CT* cp = C + (size_t)(row + i) * N + tn * 128 + wc * 64 + lq;
#pragma unroll
      for (int n = 0; n < 4; n++) {
        float v = acc[m][n][i];
        if constexpr (sizeof(CT) == 2) cp[n * 16] = (CT)f2bf(v);
        else                            cp[n * 16] = (CT)v;
      }
    }
  }
}

// ---------------- flash attention ----------------
// Q: (B,2048,16,64) bf16; KV: (B,2048,2048) bf16 with K at col h*64+d, V at 1024+h*64+d
// O: (B,2048,16,64) bf16. Block = 64 q-rows (4 waves x 16), 32 KV tiles of 64.
__global__ __launch_bounds__(256) void attn_kernel(const u16* __restrict__ Q,
                                                   const u16* __restrict__ KV,
                                                   u16* __restrict__ O) {
  __shared__ u16 Ks[64 * 64];      // [key][d], chunk-XOR swizzled
  __shared__ u16 VTs[64 * 72];     // [d][key], padded stride 72
  __shared__ u16 Pq[4][16 * 72];   // per-wave P, [q][key], padded

  const int tid = threadIdx.x;
  const int wid = tid >> 6;
  const int lane = tid & 63;
  const int lg = lane >> 4, lq = lane & 15;

  // XCD-bijective swizzle: all 32 q-tiles of one (b,h) land on one XCD
  const int bi = blockIdx.x;
  const int xcd = bi & 7;
  const int j = bi >> 3;
  const int qt = j & 31;
  const int bh = xcd + 8 * (j >> 5);
  const int b = bh >> 4, h = bh & 15;

  const int q0 = qt * 64 + wid * 16;

  // Q as MFMA B-operand: lane lq = q row, k = d slice
  bf16x8 qf[2];
  {
    const u16* qp = Q + ((size_t)(b * SEQ + q0 + lq) * NH + h) * HD + lg * 8;
    qf[0] = *(const bf16x8*)qp;
    qf[1] = *(const bf16x8*)(qp + 32);
  }

  f32x4 of[4];
#pragma unroll
  for (int d = 0; d < 4; d++)
#pragma unroll
    for (int e = 0; e < 4; e++) of[d][e] = 0.f;
  float m_run = -1e30f, l_run = 0.f;

  const u16* Kbase = KV + (size_t)b * SEQ * 2048 + h * 64;
  const u16* Vbase = Kbase + 1024;

  const int kr = tid >> 3;  // 0..31
  const int kc = tid & 7;
  const int vk = tid & 63;
  const int vd = (tid >> 6) * 16;

  for (int kt = 0; kt < 32; ++kt) {
    const u16* Kt = Kbase + (size_t)kt * 64 * 2048;
    const u16* Vt = Vbase + (size_t)kt * 64 * 2048;
    __syncthreads();
    // stage K [64][64] with chunk swizzle slot = c ^ (r&7)
#pragma unroll
    for (int ii = 0; ii < 2; ++ii) {
      const int r = kr + ii * 32;
      bf16x8 kv = *(const bf16x8*)(Kt + (size_t)r * 2048 + kc * 8);
      *(bf16x8*)(Ks + r * 64 + ((kc ^ (r & 7)) * 8)) = kv;
    }
    // stage V transposed: VTs[d][key]
    {
      bf16x8 v0 = *(const bf16x8*)(Vt + (size_t)vk * 2048 + vd);
      bf16x8 v1 = *(const bf16x8*)(Vt + (size_t)vk * 2048 + vd + 8);
#pragma unroll
      for (int e = 0; e < 8; e++) VTs[(vd + e) * 72 + vk] = (u16)v0[e];
#pragma unroll
      for (int e = 0; e < 8; e++) VTs[(vd + 8 + e) * 72 + vk] = (u16)v1[e];
    }
    __syncthreads();

    // S^T = K·Q^T : C row = key(4*lg+e within kb*16), col = q(lq)
    f32x4 sacc[4];
#pragma unroll
    for (int kb = 0; kb < 4; kb++)
#pragma unroll
      for (int e = 0; e < 4; e++) sacc[kb][e] = 0.f;
#pragma unroll
    for (int s = 0; s < 2; s++) {
      const int slotbase = 4 * s + lg;
#pragma unroll
      for (int kb = 0; kb < 4; kb++) {
        const int r = kb * 16 + lq;
        bf16x8 kf = *(const bf16x8*)(Ks + r * 64 + ((slotbase ^ (lq & 7)) * 8));
        sacc[kb] = __builtin_amdgcn_mfma_f32_16x16x32_bf16(kf, qf[s], sacc[kb], 0, 0, 0);
      }
    }

    // online softmax; lane's q = lq, replicated across the 4 lane-groups
    float tmax = -1e30f;
#pragma unroll
    for (int kb = 0; kb < 4; kb++)
#pragma unroll
      for (int e = 0; e < 4; e++) {
        sacc[kb][e] *= SCALE;
        tmax = fmaxf(tmax, sacc[kb][e]);
      }
    tmax = fmaxf(tmax, __shfl_xor(tmax, 16));
    tmax = fmaxf(tmax, __shfl_xor(tmax, 32));
    const float m_new = fmaxf(m_run, tmax);
    const float esc = __expf(m_run - m_new);
    m_run = m_new;

    float psum = 0.f;
    u16 pb[4][4];
#pragma unroll
    for (int kb = 0; kb < 4; kb++)
#pragma unroll
      for (int e = 0; e < 4; e++) {
        float p = __expf(sacc[kb][e] - m_new);
        psum += p;
        pb[kb][e] = f2bf(p);
      }
    psum += __shfl_xor(psum, 16);
    psum += __shfl_xor(psum, 32);
    l_run = l_run * esc + psum;

    // write P q-major: Pq[q=lq][key = kb*16 + 4*lg + e], packed b64
    u16* pw = &Pq[wid][lq * 72 + lg * 4];
#pragma unroll
    for (int kb = 0; kb < 4; kb++) {
      bf16x4 w;
      w[0] = (short)pb[kb][0]; w[1] = (short)pb[kb][1];
      w[2] = (short)pb[kb][2]; w[3] = (short)pb[kb][3];
      *(bf16x4*)(pw + kb * 16) = w;
    }

    // rescale O accumulator (O rows are q = 4*lg + e)
    float esc_i[4];
#pragma unroll
    for (int e = 0; e < 4; e++) esc_i[e] = __shfl(esc, lg * 4 + e);
#pragma unroll
    for (int d = 0; d < 4; d++)
#pragma unroll
      for (int e = 0; e < 4; e++) of[d][e] *= esc_i[e];

    // O += P @ V  (A = P from Pq, B = V from VTs; same-wave LDS RAW, compiler orders)
#pragma unroll
    for (int ks = 0; ks < 2; ks++) {
      bf16x8 pf = *(const bf16x8*)(&Pq[wid][lq * 72 + ks * 32 + lg * 8]);
#pragma unroll
      for (int d = 0; d < 4; d++) {
        bf16x8 vf = *(const bf16x8*)(VTs + (d * 16 + lq) * 72 + ks * 32 + lg * 8);
        of[d] = __builtin_amdgcn_mfma_f32_16x16x32_bf16(pf, vf, of[d], 0, 0, 0);
      }
    }
  }

  float linv[4];
#pragma unroll
  for (int e = 0; e < 4; e++) linv[e] = 1.f / __shfl(l_run, lg * 4 + e);
#pragma unroll
  for (int e = 0; e < 4; e++) {
    u16* op = O + ((size_t)(b * SEQ + q0 + lg * 4 + e) * NH + h) * HD + lq;
#pragma unroll
    for (int d = 0; d < 4; d++) op[d * 16] = f2bf(of[d][e] * linv[e]);
  }
}

// ---------------- launch ----------------
extern "C" void kernel_launch(void* const* d_in, const int* in_sizes, int n_in,
                              void* d_out, int out_size, void* d_ws, size_t ws_size,
                              hipStream_t stream) {
  const float* x   = (const float*)d_in[0];
  const float* z   = (const float*)d_in[1];
  const float* Wq  = (const float*)d_in[2];
  const float* Wkv = (const float*)d_in[3];
  const float* Wo  = (const float*)d_in[4];
  float* out = (float*)d_out;

  char* ws = (char*)d_ws;
  const size_t MB = 1024ull * 1024ull;
  u16* xb   = (u16*)(ws + 0);        // 8 MB  (4096x1024)
  u16* zb   = (u16*)(ws + 8 * MB);   // 4 MB  (4096x512)
  u16* Wqb  = (u16*)(ws + 12 * MB);  // 2 MB
  u16* Wkvb = (u16*)(ws + 14 * MB);  // 2 MB
  u16* Wob  = (u16*)(ws + 16 * MB);  // 2 MB
  u16* Qb   = (u16*)(ws + 18 * MB);  // 8 MB  (4096x1024)
  u16* KVb  = (u16*)(ws + 26 * MB);  // 16 MB (4096x2048)
  u16* Ob   = (u16*)(ws + 42 * MB);  // 8 MB  (4096x1024)

  auto cvt = [&](const float* src, u16* dst, int n) {
    int n4 = n / 4;
    int grid = (n4 + 255) / 256;
    if (grid > 4096) grid = 4096;
    cvt_kernel<<<grid, 256, 0, stream>>>(src, dst, n4);
  };
  cvt(x,   xb,   2 * 2048 * 1024);
  cvt(z,   zb,   2 * 2048 * 512);
  cvt(Wq,  Wqb,  1024 * 1024);
  cvt(Wkv, Wkvb, 2048 * 512);
  cvt(Wo,  Wob,  1024 * 1024);

  gemm_bt<u16><<<dim3(1024 / 128, 4096 / 128), 256, 0, stream>>>(xb, Wqb, Qb, 1024, 1024);
  gemm_bt<u16><<<dim3(2048 / 128, 4096 / 128), 256, 0, stream>>>(zb, Wkvb, KVb, 2048, 512);
  attn_kernel<<<1024, 256, 0, stream>>>(Qb, KVb, Ob);
  gemm_bt<float><<<dim3(1024 / 128, 4096 / 128), 256, 0, stream>>>(Ob, Wob, out, 1024, 1024);
}

// Round 2
// 154.641 us; speedup vs baseline: 1.1291x; 1.1291x over previous
//
#include <hip/hip_runtime.h>
#include <stdint.h>

#define NH 16
#define HD 64
#define SEQ 2048

typedef __attribute__((ext_vector_type(8))) short bf16x8;
typedef __attribute__((ext_vector_type(4))) short bf16x4;
typedef __attribute__((ext_vector_type(4))) float f32x4;
typedef unsigned short u16;

__device__ __forceinline__ u16 f2bf(float f) {
  union { float f; uint32_t u; } v; v.f = f;
  uint32_t u = v.u;
  u += 0x7fffu + ((u >> 16) & 1u);   // RNE
  return (u16)(u >> 16);
}

__device__ __forceinline__ void gload_lds16(const u16* g, u16* l) {
  __builtin_amdgcn_global_load_lds((__attribute__((address_space(1))) void*)g,
                                   (__attribute__((address_space(3))) void*)l,
                                   16, 0, 0);
}

// ---------------- fused fp32 -> bf16 convert (all 5 tensors, 1 launch) -----
__global__ void cvt5_kernel(const float* __restrict__ x, const float* __restrict__ z,
                            const float* __restrict__ Wq, const float* __restrict__ Wkv,
                            const float* __restrict__ Wo,
                            u16* __restrict__ xb, u16* __restrict__ zb,
                            u16* __restrict__ wqb, u16* __restrict__ wkvb,
                            u16* __restrict__ wob) {
  const int X4 = 1048576, Z4 = 524288, W4 = 262144;   // float4 counts
  const int total = X4 + Z4 + 3 * W4;
  int i = blockIdx.x * blockDim.x + threadIdx.x;
  const int stride = gridDim.x * blockDim.x;
  for (; i < total; i += stride) {
    const float* src; u16* dst; int j = i;
    if (j < X4)              { src = x;   dst = xb; }
    else if ((j -= X4) < Z4) { src = z;   dst = zb; }
    else if ((j -= Z4) < W4) { src = Wq;  dst = wqb; }
    else if ((j -= W4) < W4) { src = Wkv; dst = wkvb; }
    else       { j -= W4;      src = Wo;  dst = wob; }
    float4 v = ((const float4*)src)[j];
    bf16x4 o;
    o[0] = (short)f2bf(v.x); o[1] = (short)f2bf(v.y);
    o[2] = (short)f2bf(v.z); o[3] = (short)f2bf(v.w);
    ((bf16x4*)dst)[j] = o;
  }
}

// ---------------- C = scale * A(MxK) @ B(NxK)^T, bf16 in, CT out ----------
template <typename CT>
__global__ __launch_bounds__(256) void gemm_bt(const u16* __restrict__ A,
                                               const u16* __restrict__ B,
                                               CT* __restrict__ C,
                                               int N, int K, float scale) {
  __shared__ __align__(16) u16 As[128 * 32];
  __shared__ __align__(16) u16 Bs[128 * 32];
  const int tid = threadIdx.x;
  const int wid = tid >> 6;
  const int lane = tid & 63;
  const int lg = lane >> 4, lq = lane & 15;
  const int wr = wid >> 1, wc = wid & 1;
  const int tm = blockIdx.y, tn = blockIdx.x;

  f32x4 acc[4][4];
#pragma unroll
  for (int m = 0; m < 4; m++)
#pragma unroll
    for (int n = 0; n < 4; n++)
#pragma unroll
      for (int e = 0; e < 4; e++) acc[m][n][e] = 0.f;

  const int r0 = tid >> 2;
  const int s0 = tid & 3;
  const int sc = (s0 ^ ((r0 >> 1) & 3)) * 8;
  const u16* gA0 = A + (size_t)(tm * 128 + r0) * K + sc;
  const u16* gA1 = A + (size_t)(tm * 128 + r0 + 64) * K + sc;
  const u16* gB0 = B + (size_t)(tn * 128 + r0) * K + sc;
  const u16* gB1 = B + (size_t)(tn * 128 + r0 + 64) * K + sc;
  u16* lA = As + wid * 512;
  u16* lB = Bs + wid * 512;

  const int rslot = (lg ^ ((lq >> 1) & 3)) * 8;

  for (int k0 = 0; k0 < K; k0 += 32) {
    __syncthreads();
    gload_lds16(gA0 + k0, lA);
    gload_lds16(gA1 + k0, lA + 2048);
    gload_lds16(gB0 + k0, lB);
    gload_lds16(gB1 + k0, lB + 2048);
    __syncthreads();

    bf16x8 af[4], bfr[4];
#pragma unroll
    for (int m = 0; m < 4; m++)
      af[m] = *(const bf16x8*)(As + (wr * 64 + m * 16 + lq) * 32 + rslot);
#pragma unroll
    for (int n = 0; n < 4; n++)
      bfr[n] = *(const bf16x8*)(Bs + (wc * 64 + n * 16 + lq) * 32 + rslot);
#pragma unroll
    for (int m = 0; m < 4; m++)
#pragma unroll
      for (int n = 0; n < 4; n++)
        acc[m][n] = __builtin_amdgcn_mfma_f32_16x16x32_bf16(af[m], bfr[n], acc[m][n], 0, 0, 0);
  }

#pragma unroll
  for (int m = 0; m < 4; m++) {
    const int row = tm * 128 + wr * 64 + m * 16 + lg * 4;
#pragma unroll
    for (int i = 0; i < 4; i++) {
      CT* cp = C + (size_t)(row + i) * N + tn * 128 + wc * 64 + lq;
#pragma unroll
      for (int n = 0; n < 4; n++) {
        float v = acc[m][n][i] * scale;
        if constexpr (sizeof(CT) == 2) cp[n * 16] = (CT)f2bf(v);
        else                            cp[n * 16] = (CT)v;
      }
    }
  }
}

// ---------------- flash attention ----------------
// Q : [B*SEQ][1024] bf16 (pre-scaled by 0.125 in Q-GEMM)
// K : [B*SEQ][1024] bf16 (col = h*64+d)
// VT: [1024][B*SEQ]  bf16 (row = h*64+d, col = b*2048+token)
// O : [B*SEQ][1024] bf16
__global__ __launch_bounds__(256) void attn_kernel(const u16* __restrict__ Q,
                                                   const u16* __restrict__ K,
                                                   const u16* __restrict__ VT,
                                                   u16* __restrict__ O) {
  __shared__ __align__(16) u16 Ks[2][64 * 64];
  __shared__ __align__(16) u16 Vs[2][64 * 64];
  __shared__ __align__(16) u16 Pq[4][16 * 64];

  const int tid = threadIdx.x;
  const int wid = tid >> 6;
  const int lane = tid & 63;
  const int lg = lane >> 4, lq = lane & 15;

  // XCD-bijective swizzle: all 32 q-tiles of one (b,h) on one XCD
  const int bi = blockIdx.x;
  const int xcd = bi & 7;
  const int j = bi >> 3;
  const int qt = j & 31;
  const int bh = xcd + 8 * (j >> 5);
  const int b = bh >> 4, h = bh & 15;

  const int q0 = qt * 64 + wid * 16;

  // Q fragment (B-operand): lane lq = q row, k-elems = d slices
  bf16x8 qf[2];
  {
    const u16* qp = Q + (size_t)(b * SEQ + q0 + lq) * 1024 + h * 64 + lg * 8;
    qf[0] = *(const bf16x8*)qp;
    qf[1] = *(const bf16x8*)(qp + 32);
  }

  f32x4 of[4];
#pragma unroll
  for (int d = 0; d < 4; d++)
#pragma unroll
    for (int e = 0; e < 4; e++) of[d][e] = 0.f;
  float m_run = -1e30f, l_run = 0.f;

  // staging source addressing (pre-swizzled global -> linear LDS)
  const int r0 = tid >> 3;                 // 0..31
  const int s0 = tid & 7;                  // chunk slot
  const int ksl = (s0 ^ (r0 & 7)) * 8;
  const u16* gK = K + (size_t)(b * SEQ + r0) * 1024 + h * 64 + ksl;
  const u16* gV = VT + (size_t)(h * 64 + r0) * 4096 + b * SEQ + ksl;
  u16* lK = (u16*)Ks + wid * 512;          // wave-uniform dest chunk
  u16* lV = (u16*)Vs + wid * 512;

  auto stage = [&](int t, int buf) {
    const u16* sk = gK + (size_t)t * 64 * 1024;
    gload_lds16(sk, lK + buf * 4096);
    gload_lds16(sk + 32 * 1024, lK + buf * 4096 + 2048);
    const u16* sv = gV + t * 64;
    gload_lds16(sv, lV + buf * 4096);
    gload_lds16(sv + (size_t)32 * 4096, lV + buf * 4096 + 2048);
  };

  u16* pqrow = &Pq[wid][lq * 64];

  auto tile_compute = [&](const u16* Kb, const u16* Vb) {
    f32x4 sacc[4];
#pragma unroll
    for (int kb = 0; kb < 4; kb++)
#pragma unroll
      for (int e = 0; e < 4; e++) sacc[kb][e] = 0.f;
#pragma unroll
    for (int s = 0; s < 2; s++) {
#pragma unroll
      for (int kb = 0; kb < 4; kb++) {
        bf16x8 kf = *(const bf16x8*)(Kb + (kb * 16 + lq) * 64 + (((s * 4 + lg) ^ (lq & 7)) << 3));
        sacc[kb] = __builtin_amdgcn_mfma_f32_16x16x32_bf16(kf, qf[s], sacc[kb], 0, 0, 0);
      }
    }

    float tmax = -1e30f;
#pragma unroll
    for (int kb = 0; kb < 4; kb++)
#pragma unroll
      for (int e = 0; e < 4; e++) tmax = fmaxf(tmax, sacc[kb][e]);
    tmax = fmaxf(tmax, __shfl_xor(tmax, 16));
    tmax = fmaxf(tmax, __shfl_xor(tmax, 32));

    if (!__all(tmax <= m_run + 8.f)) {        // defer-max (T13)
      const float m_new = fmaxf(m_run, tmax);
      const float esc = __expf(m_run - m_new);
      l_run *= esc;
      const float e0 = __shfl(esc, lg * 4 + 0), e1 = __shfl(esc, lg * 4 + 1);
      const float e2 = __shfl(esc, lg * 4 + 2), e3 = __shfl(esc, lg * 4 + 3);
#pragma unroll
      for (int d = 0; d < 4; d++) {
        of[d][0] *= e0; of[d][1] *= e1; of[d][2] *= e2; of[d][3] *= e3;
      }
      m_run = m_new;
    }

    float psum = 0.f;
#pragma unroll
    for (int kb = 0; kb < 4; kb++) {
      float p0 = __expf(sacc[kb][0] - m_run);
      float p1 = __expf(sacc[kb][1] - m_run);
      float p2 = __expf(sacc[kb][2] - m_run);
      float p3 = __expf(sacc[kb][3] - m_run);
      psum += (p0 + p1) + (p2 + p3);
      uint32_t w01, w23;
      asm("v_cvt_pk_bf16_f32 %0, %1, %2" : "=v"(w01) : "v"(p0), "v"(p1));
      asm("v_cvt_pk_bf16_f32 %0, %1, %2" : "=v"(w23) : "v"(p2), "v"(p3));
      const int c = (kb * 4 + lg) ^ ((lq & 7) << 1);   // swizzled 8B-chunk slot
      *(uint2*)(pqrow + c * 4) = make_uint2(w01, w23);
    }
    psum += __shfl_xor(psum, 16);
    psum += __shfl_xor(psum, 32);
    l_run += psum;

#pragma unroll
    for (int ks = 0; ks < 2; ks++) {
      const int c0 = (ks * 8 + lg * 2) ^ ((lq & 7) << 1);
      bf16x8 pf = *(const bf16x8*)(pqrow + c0 * 4);
#pragma unroll
      for (int db = 0; db < 4; db++) {
        bf16x8 vf = *(const bf16x8*)(Vb + (db * 16 + lq) * 64 + (((ks * 4 + lg) ^ (lq & 7)) << 3));
        of[db] = __builtin_amdgcn_mfma_f32_16x16x32_bf16(pf, vf, of[db], 0, 0, 0);
      }
    }
  };

  stage(0, 0);
  __syncthreads();
  for (int kt = 0; kt < 32; kt += 2) {
    stage(kt + 1, 1);
    tile_compute(&Ks[0][0], &Vs[0][0]);
    __syncthreads();
    if (kt + 2 < 32) stage(kt + 2, 0);
    tile_compute(&Ks[1][0], &Vs[1][0]);
    __syncthreads();
  }

  float linv[4];
#pragma unroll
  for (int e = 0; e < 4; e++) linv[e] = 1.f / __shfl(l_run, lg * 4 + e);
#pragma unroll
  for (int e = 0; e < 4; e++) {
    u16* op = O + (size_t)(b * SEQ + q0 + lg * 4 + e) * 1024 + h * 64 + lq;
#pragma unroll
    for (int d = 0; d < 4; d++) op[d * 16] = f2bf(of[d][e] * linv[e]);
  }
}

// ---------------- launch ----------------
extern "C" void kernel_launch(void* const* d_in, const int* in_sizes, int n_in,
                              void* d_out, int out_size, void* d_ws, size_t ws_size,
                              hipStream_t stream) {
  const float* x   = (const float*)d_in[0];
  const float* z   = (const float*)d_in[1];
  const float* Wq  = (const float*)d_in[2];
  const float* Wkv = (const float*)d_in[3];
  const float* Wo  = (const float*)d_in[4];
  float* out = (float*)d_out;

  char* ws = (char*)d_ws;
  const size_t MB = 1024ull * 1024ull;
  u16* xb   = (u16*)(ws + 0);        // 8 MB  [4096][1024]
  u16* zb   = (u16*)(ws + 8 * MB);   // 4 MB  [4096][512]
  u16* Wqb  = (u16*)(ws + 12 * MB);  // 2 MB
  u16* Wkvb = (u16*)(ws + 14 * MB);  // 2 MB
  u16* Wob  = (u16*)(ws + 16 * MB);  // 2 MB
  u16* Qb   = (u16*)(ws + 18 * MB);  // 8 MB  [4096][1024] (pre-scaled)
  u16* Kb   = (u16*)(ws + 26 * MB);  // 8 MB  [4096][1024]
  u16* VTb  = (u16*)(ws + 34 * MB);  // 8 MB  [1024][4096]
  u16* Ob   = (u16*)(ws + 42 * MB);  // 8 MB  [4096][1024]

  cvt5_kernel<<<2048, 256, 0, stream>>>(x, z, Wq, Wkv, Wo, xb, zb, Wqb, Wkvb, Wob);

  // Q = 0.125 * x @ Wq^T
  gemm_bt<u16><<<dim3(8, 32), 256, 0, stream>>>(xb, Wqb, Qb, 1024, 1024, 0.125f);
  // K = z @ Wk^T
  gemm_bt<u16><<<dim3(8, 32), 256, 0, stream>>>(zb, Wkvb, Kb, 1024, 512, 1.f);
  // VT = Wv @ z^T  (V transposed for free by operand swap)
  gemm_bt<u16><<<dim3(32, 8), 256, 0, stream>>>(Wkvb + 1024 * 512, zb, VTb, 4096, 512, 1.f);

  attn_kernel<<<1024, 256, 0, stream>>>(Qb, Kb, VTb, Ob);

  // out = O @ Wo^T (fp32 out)
  gemm_bt<float><<<dim3(8, 32), 256, 0, stream>>>(Ob, Wob, out, 1024, 1024, 1.f);
}

// Round 5
// 117.335 us; speedup vs baseline: 1.4882x; 1.3179x over previous
//
#include <hip/hip_runtime.h>
#include <stdint.h>

#define SEQ 2048
#define QSCALE 0.1803368801111244f   // 0.125 * log2(e)
#define DEFER_THR 11.5f              // 8 nats in log2 units

typedef __attribute__((ext_vector_type(8))) short bf16x8;
typedef __attribute__((ext_vector_type(4))) short bf16x4;
typedef __attribute__((ext_vector_type(4))) float f32x4;
typedef __attribute__((ext_vector_type(16))) float f32x16;
typedef unsigned short u16;

__device__ __forceinline__ u16 f2bf(float f) {
  union { float f; uint32_t u; } v; v.f = f;
  uint32_t u = v.u;
  u += 0x7fffu + ((u >> 16) & 1u);   // RNE
  return (u16)(u >> 16);
}

__device__ __forceinline__ float fast_exp2(float x) {
#if __has_builtin(__builtin_amdgcn_exp2f)
  return __builtin_amdgcn_exp2f(x);   // v_exp_f32 (native base-2)
#else
  return exp2f(x);
#endif
}

__device__ __forceinline__ uint32_t cvtpk(float a, float b) {
  uint32_t r;
  asm("v_cvt_pk_bf16_f32 %0, %1, %2" : "=v"(r) : "v"(a), "v"(b));
  return r;
}

// exchange across lane<->lane^32 via verified __shfl_xor:
// a' = (hi ? partner_b : a), b' = (hi ? b : partner_a)
__device__ __forceinline__ void swap_pair(uint32_t& a, uint32_t& b, int hi) {
  uint32_t ta = (uint32_t)__shfl_xor((int)a, 32);
  uint32_t tb = (uint32_t)__shfl_xor((int)b, 32);
  a = hi ? tb : a;
  b = hi ? b : ta;
}

__device__ __forceinline__ void gload_lds16(const u16* g, u16* l) {
  __builtin_amdgcn_global_load_lds((__attribute__((address_space(1))) void*)g,
                                   (__attribute__((address_space(3))) void*)l,
                                   16, 0, 0);
}

// ---------------- fused fp32 -> bf16 convert (all 5 tensors, 1 launch) -----
__global__ void cvt5_kernel(const float* __restrict__ x, const float* __restrict__ z,
                            const float* __restrict__ Wq, const float* __restrict__ Wkv,
                            const float* __restrict__ Wo,
                            u16* __restrict__ xb, u16* __restrict__ zb,
                            u16* __restrict__ wqb, u16* __restrict__ wkvb,
                            u16* __restrict__ wob) {
  const int X4 = 1048576, Z4 = 524288, W4 = 262144;
  const int total = X4 + Z4 + 3 * W4;
  int i = blockIdx.x * blockDim.x + threadIdx.x;
  const int stride = gridDim.x * blockDim.x;
  for (; i < total; i += stride) {
    const float* src; u16* dst; int j = i;
    if (j < X4)              { src = x;   dst = xb; }
    else if ((j -= X4) < Z4) { src = z;   dst = zb; }
    else if ((j -= Z4) < W4) { src = Wq;  dst = wqb; }
    else if ((j -= W4) < W4) { src = Wkv; dst = wkvb; }
    else       { j -= W4;      src = Wo;  dst = wob; }
    float4 v = ((const float4*)src)[j];
    bf16x4 o;
    o[0] = (short)f2bf(v.x); o[1] = (short)f2bf(v.y);
    o[2] = (short)f2bf(v.z); o[3] = (short)f2bf(v.w);
    ((bf16x4*)dst)[j] = o;
  }
}

// ---------------- C = scale * A(MxK) @ B(NxK)^T body, 128xBN tile ----------
template <int BN, typename CT>
__device__ __forceinline__ void gemm_bt_body(const u16* __restrict__ A,
                                             const u16* __restrict__ B,
                                             CT* __restrict__ C,
                                             int N, int K, float scale,
                                             int tm, int tn, u16* As, u16* Bs) {
  constexpr int NB = BN / 32;    // N-fragments per wave
  constexpr int NBG = BN / 64;   // B staging gloads
  const int tid = threadIdx.x;
  const int wid = tid >> 6;
  const int lane = tid & 63;
  const int lg = lane >> 4, lq = lane & 15;
  const int wr = wid >> 1, wc = wid & 1;

  f32x4 acc[4][NB];
#pragma unroll
  for (int m = 0; m < 4; m++)
#pragma unroll
    for (int n = 0; n < NB; n++)
#pragma unroll
      for (int e = 0; e < 4; e++) acc[m][n][e] = 0.f;

  const int r0 = tid >> 2;
  const int s0 = tid & 3;
  const int sc = (s0 ^ ((r0 >> 1) & 3)) * 8;
  const u16* gA0 = A + (size_t)(tm * 128 + r0) * K + sc;
  const u16* gA1 = gA0 + (size_t)64 * K;
  const u16* gB0 = B + (size_t)(tn * BN + r0) * K + sc;
  const u16* gB1 = gB0 + (size_t)64 * K;
  u16* lA = As + wid * 512;
  u16* lB = Bs + wid * 512;

  const int rslot = (lg ^ ((lq >> 1) & 3)) * 8;

  for (int k0 = 0; k0 < K; k0 += 32) {
    __syncthreads();
    gload_lds16(gA0 + k0, lA);
    gload_lds16(gA1 + k0, lA + 2048);
    gload_lds16(gB0 + k0, lB);
    if constexpr (NBG == 2) gload_lds16(gB1 + k0, lB + 2048);
    __syncthreads();

    bf16x8 af[4], bfr[NB];
#pragma unroll
    for (int m = 0; m < 4; m++)
      af[m] = *(const bf16x8*)(As + (wr * 64 + m * 16 + lq) * 32 + rslot);
#pragma unroll
    for (int n = 0; n < NB; n++)
      bfr[n] = *(const bf16x8*)(Bs + (wc * (BN / 2) + n * 16 + lq) * 32 + rslot);
#pragma unroll
    for (int m = 0; m < 4; m++)
#pragma unroll
      for (int n = 0; n < NB; n++)
        acc[m][n] = __builtin_amdgcn_mfma_f32_16x16x32_bf16(af[m], bfr[n], acc[m][n], 0, 0, 0);
  }

#pragma unroll
  for (int m = 0; m < 4; m++) {
    const int row = tm * 128 + wr * 64 + m * 16 + lg * 4;
#pragma unroll
    for (int i = 0; i < 4; i++) {
      CT* cp = C + (size_t)(row + i) * N + tn * BN + wc * (BN / 2) + lq;
#pragma unroll
      for (int n = 0; n < NB; n++) {
        float v = acc[m][n][i] * scale;
        if constexpr (sizeof(CT) == 2) cp[n * 16] = (CT)f2bf(v);
        else                            cp[n * 16] = (CT)v;
      }
    }
  }
}

// ---------------- fused Q/K/VT projection GEMMs (768 blocks) ----------------
__global__ __launch_bounds__(256) void qkv_gemm(const u16* __restrict__ xb,
                                                const u16* __restrict__ zb,
                                                const u16* __restrict__ Wqb,
                                                const u16* __restrict__ Wkvb,
                                                u16* __restrict__ Qb,
                                                u16* __restrict__ Kb,
                                                u16* __restrict__ VTb) {
  __shared__ __align__(16) u16 As[128 * 32];
  __shared__ __align__(16) u16 Bs[128 * 32];
  int g = blockIdx.x;
  if (g < 256) {
    // Q = (0.125*log2e) * x @ Wq^T   [4096 x 1024]
    gemm_bt_body<128, u16>(xb, Wqb, Qb, 1024, 1024, QSCALE, g >> 3, g & 7, As, Bs);
  } else if (g < 512) {
    g -= 256;  // K = z @ Wk^T   [4096 x 1024]
    gemm_bt_body<128, u16>(zb, Wkvb, Kb, 1024, 512, 1.f, g >> 3, g & 7, As, Bs);
  } else {
    g -= 512;  // VT = Wv @ z^T  [1024 x 4096]
    gemm_bt_body<128, u16>(Wkvb + 1024 * 512, zb, VTb, 4096, 512, 1.f, g >> 5, g & 31, As, Bs);
  }
}

// ---------------- O-GEMM: out = O @ Wo^T, fp32 out, 128x64 tiles ------------
__global__ __launch_bounds__(256) void o_gemm(const u16* __restrict__ Ob,
                                              const u16* __restrict__ Wob,
                                              float* __restrict__ out) {
  __shared__ __align__(16) u16 As[128 * 32];
  __shared__ __align__(16) u16 Bs[64 * 32];
  gemm_bt_body<64, float>(Ob, Wob, out, 1024, 1024, 1.f, blockIdx.y, blockIdx.x, As, Bs);
}

// ---------------- flash attention (32x32 MFMA, in-register P) ---------------
// Q : [B*SEQ][1024] bf16, pre-scaled by 0.125*log2e
// K : [B*SEQ][1024] bf16
// VT: [1024][B*SEQ]  bf16
// O : [B*SEQ][1024] bf16
// 512 blocks, 4 waves x 32 q-rows = 128 q/block, KV tiles of 64, double-buffered.
__global__ __launch_bounds__(256) void attn_kernel(const u16* __restrict__ Q,
                                                   const u16* __restrict__ K,
                                                   const u16* __restrict__ VT,
                                                   u16* __restrict__ O) {
  // u16 offsets: K0 @0, K1 @4096, V0 @8192, V1 @12288
  __shared__ __align__(16) u16 LDS[16384];

  const int tid = threadIdx.x;
  const int wid = tid >> 6;
  const int lane = tid & 63;
  const int l31 = lane & 31;
  const int hi = lane >> 5;

  // XCD-bijective: 4 bh x 16 qt per XCD (64 blocks/XCD = 2/CU)
  const int bi = blockIdx.x;
  const int xcd = bi & 7, j = bi >> 3;
  const int qt = j & 15;
  const int bh = xcd + 8 * (j >> 4);
  const int b = bh >> 4, h = bh & 15;

  const int q0 = qt * 128 + wid * 32;

  // Q fragments (B-operand): col q = l31, k-elems d = ks*16 + hi*8 .. +7
  bf16x8 qf[4];
  {
    const u16* qp = Q + (size_t)(b * SEQ + q0 + l31) * 1024 + h * 64 + hi * 8;
#pragma unroll
    for (int ks = 0; ks < 4; ks++) qf[ks] = *(const bf16x8*)(qp + ks * 16);
  }

  f32x16 of[2];
#pragma unroll
  for (int d = 0; d < 2; d++)
#pragma unroll
    for (int e = 0; e < 16; e++) of[d][e] = 0.f;
  float m_run = -3.0e38f, l_run = 0.f;

  // tile-invariant per-lane LDS read bases: row l31, swizzled chunk (2ks+hi)^(lane&7)
  const char* rdB[4];
#pragma unroll
  for (int ks = 0; ks < 4; ks++)
    rdB[ks] = (const char*)LDS + l31 * 128 + ((((2 * ks + hi) ^ (lane & 7))) << 4);

  // staging: wave w stages rows 8w..8w+7 (+32), pre-swizzled source column
  const int r0 = tid >> 3;
  const int srcc = ((tid & 7) ^ (r0 & 7)) << 3;
  const u16* gK = K + (size_t)(b * SEQ + r0) * 1024 + h * 64 + srcc;
  const u16* gV = VT + (size_t)(h * 64 + r0) * 4096 + b * SEQ + srcc;
  u16* lK = LDS + wid * 512;
  u16* lV = LDS + 8192 + wid * 512;

  auto stage = [&](int t, int buf) {
    const u16* sk = gK + (size_t)t * 64 * 1024;
    gload_lds16(sk, lK + buf * 4096);
    gload_lds16(sk + (size_t)32 * 1024, lK + buf * 4096 + 2048);
    const u16* sv = gV + t * 64;
    gload_lds16(sv, lV + buf * 4096);
    gload_lds16(sv + (size_t)32 * 4096, lV + buf * 4096 + 2048);
  };

  auto tile_compute = [&](int buf) {
    const int bo = buf * 8192;   // bytes

    // S^T = K (A) x Q (B): C col = q = l31, row = key = kb*32 + (r&3)+8*(r>>2)+4*hi
    f32x16 sacc[2];
#pragma unroll
    for (int kb = 0; kb < 2; kb++)
#pragma unroll
      for (int e = 0; e < 16; e++) sacc[kb][e] = 0.f;
    __builtin_amdgcn_s_setprio(1);
#pragma unroll
    for (int kb = 0; kb < 2; kb++)
#pragma unroll
      for (int ks = 0; ks < 4; ks++) {
        bf16x8 kf = *(const bf16x8*)(rdB[ks] + bo + kb * 4096);
        sacc[kb] = __builtin_amdgcn_mfma_f32_32x32x16_bf16(kf, qf[ks], sacc[kb], 0, 0, 0);
      }
    __builtin_amdgcn_s_setprio(0);

    // per-lane max over 32 scores, then combine across the lane^32 pair
    float tmax = sacc[0][0];
#pragma unroll
    for (int e = 1; e < 16; e++) tmax = fmaxf(tmax, sacc[0][e]);
#pragma unroll
    for (int e = 0; e < 16; e++) tmax = fmaxf(tmax, sacc[1][e]);
    tmax = fmaxf(tmax, __shfl_xor(tmax, 32));

    if (!__all(tmax <= m_run + DEFER_THR)) {
      const float m_new = fmaxf(m_run, tmax);
      const float esc = fast_exp2(m_run - m_new);
      l_run *= esc;
#pragma unroll
      for (int r = 0; r < 16; r++) {
        const int qof = (r & 3) + 8 * (r >> 2) + 4 * hi;
        const float e = __shfl(esc, qof);
        of[0][r] *= e;
        of[1][r] *= e;
      }
      m_run = m_new;
    }

    // p = exp2(s - m), in place; accumulate lane-partial row sum
    float psum = 0.f;
#pragma unroll
    for (int kb = 0; kb < 2; kb++)
#pragma unroll
      for (int e = 0; e < 16; e++) {
        float p = fast_exp2(sacc[kb][e] - m_run);
        sacc[kb][e] = p;
        psum += p;
      }
    l_run += psum;

    // pack P to bf16 A-fragments fully in-register (cvt_pk + shfl_xor exchange)
    bf16x8 pa[4];
#pragma unroll
    for (int kb = 0; kb < 2; kb++) {
      uint32_t c0 = cvtpk(sacc[kb][0],  sacc[kb][1]);   // keys {0,1}  (+4 if hi)
      uint32_t c1 = cvtpk(sacc[kb][2],  sacc[kb][3]);   // keys {2,3}
      uint32_t c2 = cvtpk(sacc[kb][4],  sacc[kb][5]);   // keys {8,9}
      uint32_t c3 = cvtpk(sacc[kb][6],  sacc[kb][7]);   // keys {10,11}
      uint32_t c4 = cvtpk(sacc[kb][8],  sacc[kb][9]);   // keys {16,17}
      uint32_t c5 = cvtpk(sacc[kb][10], sacc[kb][11]);  // keys {18,19}
      uint32_t c6 = cvtpk(sacc[kb][12], sacc[kb][13]);  // keys {24,25}
      uint32_t c7 = cvtpk(sacc[kb][14], sacc[kb][15]);  // keys {26,27}
      swap_pair(c0, c2, hi);  // lo: c0={0,1},c2={4,5}; hi: c0={8,9},c2={12,13}
      swap_pair(c1, c3, hi);
      swap_pair(c4, c6, hi);
      swap_pair(c5, c7, hi);
      union { bf16x8 v; uint32_t d[4]; } u0, u1;
      u0.d[0] = c0; u0.d[1] = c1; u0.d[2] = c2; u0.d[3] = c3;
      u1.d[0] = c4; u1.d[1] = c5; u1.d[2] = c6; u1.d[3] = c7;
      pa[2 * kb] = u0.v;
      pa[2 * kb + 1] = u1.v;
    }

    // O += P (A) x V (B): V-frag col d = db*32 + l31, k = keys
    __builtin_amdgcn_s_setprio(1);
#pragma unroll
    for (int ks = 0; ks < 4; ks++)
#pragma unroll
      for (int db = 0; db < 2; db++) {
        bf16x8 vf = *(const bf16x8*)(rdB[ks] + bo + 16384 + db * 4096);
        of[db] = __builtin_amdgcn_mfma_f32_32x32x16_bf16(pa[ks], vf, of[db], 0, 0, 0);
      }
    __builtin_amdgcn_s_setprio(0);
  };

  stage(0, 0);
  __syncthreads();
  for (int kt = 0; kt < 32; kt += 2) {
    stage(kt + 1, 1);
    tile_compute(0);
    __syncthreads();
    if (kt + 2 < 32) stage(kt + 2, 0);
    tile_compute(1);
    __syncthreads();
  }

  // final row-sum across the lane^32 pair, then normalize + write
  const float lsum = l_run + __shfl_xor(l_run, 32);
  const float linv = 1.f / lsum;

#pragma unroll
  for (int r = 0; r < 16; r++) {
    const int qof = (r & 3) + 8 * (r >> 2) + 4 * hi;
    const float li = __shfl(linv, qof);
    u16* op = O + (size_t)(b * SEQ + q0 + qof) * 1024 + h * 64 + l31;
    op[0]  = f2bf(of[0][r] * li);
    op[32] = f2bf(of[1][r] * li);
  }
}

// ---------------- launch ----------------
extern "C" void kernel_launch(void* const* d_in, const int* in_sizes, int n_in,
                              void* d_out, int out_size, void* d_ws, size_t ws_size,
                              hipStream_t stream) {
  const float* x   = (const float*)d_in[0];
  const float* z   = (const float*)d_in[1];
  const float* Wq  = (const float*)d_in[2];
  const float* Wkv = (const float*)d_in[3];
  const float* Wo  = (const float*)d_in[4];
  float* out = (float*)d_out;

  char* ws = (char*)d_ws;
  const size_t MB = 1024ull * 1024ull;
  u16* xb   = (u16*)(ws + 0);        // 8 MB  [4096][1024]
  u16* zb   = (u16*)(ws + 8 * MB);   // 4 MB  [4096][512]
  u16* Wqb  = (u16*)(ws + 12 * MB);  // 2 MB
  u16* Wkvb = (u16*)(ws + 14 * MB);  // 2 MB
  u16* Wob  = (u16*)(ws + 16 * MB);  // 2 MB
  u16* Qb   = (u16*)(ws + 18 * MB);  // 8 MB  [4096][1024] (pre-scaled, log2 domain)
  u16* Kb   = (u16*)(ws + 26 * MB);  // 8 MB  [4096][1024]
  u16* VTb  = (u16*)(ws + 34 * MB);  // 8 MB  [1024][4096]
  u16* Ob   = (u16*)(ws + 42 * MB);  // 8 MB  [4096][1024]

  cvt5_kernel<<<2048, 256, 0, stream>>>(x, z, Wq, Wkv, Wo, xb, zb, Wqb, Wkvb, Wob);

  qkv_gemm<<<768, 256, 0, stream>>>(xb, zb, Wqb, Wkvb, Qb, Kb, VTb);

  attn_kernel<<<512, 256, 0, stream>>>(Qb, Kb, VTb, Ob);

  o_gemm<<<dim3(16, 32), 256, 0, stream>>>(Ob, Wob, out);
}